// Round 1
// baseline (332.811 us; speedup 1.0000x reference)
//
#include <hip/hip_runtime.h>
#include <math.h>

#define BS 32
#define NT 50
#define NC 80
#define H 76
#define W 76
#define HW (H*W)
#define NA (5+NC)
#define SIGMA 8.0f
#define IGN_THR 0.5f

// _clog: clip(log(clip(p,1e-12,1)), -100, 0)
__device__ __forceinline__ float clog_(float p){
    p = fminf(fmaxf(p, 1e-12f), 1.0f);
    float l = logf(p);
    return fminf(fmaxf(l, -100.0f), 0.0f);
}

__device__ __forceinline__ float sigmoid_(float v){
    return 1.0f / (1.0f + expf(-v));
}

// ---------------- Kernel 1: per-batch target prep ----------------
// tdata layout per target (12 floats):
// [0]=gx1 [1]=gy1 [2]=gx2 [3]=gy2 [4]=garea [5]=cell(float)
// [6]=tx [7]=ty [8]=tw [9]=th [10]=scale [11]=cls(float)
__global__ void prep_targets(const float* __restrict__ targets,
                             float* __restrict__ tdata,
                             int* __restrict__ counts,
                             int* __restrict__ n_obj){
    int b = blockIdx.x;
    int t = threadIdx.x;
    __shared__ int s_cell[NT];
    __shared__ unsigned char s_valid[NT];
    __shared__ int s_count;
    if (t == 0) s_count = 0;

    float cls=0.f, xx=0.f, yy=0.f, ww=0.f, hh=0.f;
    bool valid = false;
    int cell = 0;
    if (t < NT){
        const float* p = targets + ((size_t)b*NT + t)*5;
        cls = p[0]; xx = p[1]; yy = p[2]; ww = p[3]; hh = p[4];
        float s = cls + xx + yy + ww + hh;
        valid = (s != 0.0f);
        float gx = xx * (float)W, gy = yy * (float)H;
        int gi = min(max((int)gx, 0), W-1);
        int gj = min(max((int)gy, 0), H-1);
        cell = gj*W + gi;
        s_cell[t] = cell;
        s_valid[t] = valid ? 1 : 0;
    }
    __syncthreads();
    if (t < NT && valid){
        bool dup = false;
        for (int u = 0; u < t; ++u)
            if (s_valid[u] && s_cell[u] == cell) dup = true;
        if (!dup){
            int idx = atomicAdd(&s_count, 1);
            float gx = xx*(float)W, gy = yy*(float)H;
            float gw = ww*(float)W, gh = hh*(float)H;
            int gi = min(max((int)gx, 0), W-1);
            int gj = min(max((int)gy, 0), H-1);
            float* d = tdata + ((size_t)b*NT + idx)*12;
            d[0]  = gx - gw*0.5f;
            d[1]  = gy - gh*0.5f;
            d[2]  = gx + gw*0.5f;
            d[3]  = gy + gh*0.5f;
            d[4]  = gw * gh;
            d[5]  = (float)cell;
            d[6]  = gx - (float)gi;                 // tx
            d[7]  = gy - (float)gj;                 // ty
            d[8]  = logf(gw/SIGMA + 1e-16f);        // tw
            d[9]  = logf(gh/SIGMA + 1e-16f);        // th
            d[10] = 2.0f - ww*hh;                   // scale
            d[11] = (float)min(max((int)cls, 0), NC-1);
        }
    }
    __syncthreads();
    if (t == 0){
        counts[b] = s_count;
        atomicAdd(n_obj, s_count);
    }
}

// ---------------- Kernel 2: per-cell main loss ----------------
// sums[0..5] = {x, y, w, h, conf, tcls} raw sums
__global__ __launch_bounds__(256) void yolo_main(
    const float* __restrict__ input,
    const float* __restrict__ tdata,
    const int*   __restrict__ counts,
    float*       __restrict__ sums)
{
    int b = blockIdx.x;
    int cell = blockIdx.y * blockDim.x + threadIdx.x;

    __shared__ float s_t[NT*12];
    __shared__ int s_nb;
    if (threadIdx.x == 0) s_nb = counts[b];
    __syncthreads();
    int nb = s_nb;
    for (int k = threadIdx.x; k < nb*12; k += blockDim.x)
        s_t[k] = tdata[(size_t)b*NT*12 + k];
    __syncthreads();

    float lx=0.f, ly=0.f, lw=0.f, lh=0.f, lc=0.f, lt=0.f;
    if (cell < HW){
        const float* base = input + (size_t)b*NA*HW + cell;
        float vx = base[0];
        float vy = base[HW];
        float vw = base[2*HW];
        float vh = base[3*HW];
        float vc = base[4*HW];
        float x    = sigmoid_(vx);
        float y    = sigmoid_(vy);
        float conf = sigmoid_(vc);
        int i = cell / W, j = cell - i*W;
        float pw = expf(vw) * SIGMA;
        float ph = expf(vh) * SIGMA;
        float px = x + (float)j;
        float py = y + (float)i;
        float px1 = px - pw*0.5f, px2 = px + pw*0.5f;
        float py1 = py - ph*0.5f, py2 = py + ph*0.5f;
        float parea = pw * ph;

        bool ignore = false;
        int myt = -1;
        for (int t = 0; t < nb; ++t){
            const float* d = s_t + t*12;
            float iw = fminf(d[2], px2) - fmaxf(d[0], px1);
            float ih = fminf(d[3], py2) - fmaxf(d[1], py1);
            iw = fmaxf(iw, 0.f); ih = fmaxf(ih, 0.f);
            float inter = iw * ih;
            float iou = inter / (d[4] + parea - inter + 1e-16f);
            ignore = ignore || (iou >= IGN_THR);
            if ((int)d[5] == cell) myt = t;
        }

        if (myt >= 0){
            const float* d = s_t + myt*12;
            float scale = d[10];
            float tx = d[6], ty = d[7];
            lx = scale * (-(tx*clog_(x) + (1.f-tx)*clog_(1.f-x)));
            ly = scale * (-(ty*clog_(y) + (1.f-ty)*clog_(1.f-y)));
            float dw = fabsf(vw - d[8]);
            lw = scale * (dw < 1.f ? 0.5f*dw*dw : dw - 0.5f);
            float dh = fabsf(vh - d[9]);
            lh = scale * (dh < 1.f ? 0.5f*dh*dh : dh - 0.5f);
            lc = -clog_(conf);
            int cidx = (int)d[11];
            const float* cb = base + 5*HW;
            float acc = 0.f;
            for (int c = 0; c < NC; ++c){
                float pc = sigmoid_(cb[(size_t)c*HW]);
                if (c == cidx) acc += -clog_(pc);
                else           acc += -clog_(1.f - pc);
            }
            lt = acc;
        } else if (!ignore){
            lc = 0.5f * (-clog_(1.0f - conf));
        }
    }

    // wave (64-lane) shuffle reduction, then one atomic per wave per sum
    #pragma unroll
    for (int off = 32; off > 0; off >>= 1){
        lx += __shfl_down(lx, off);
        ly += __shfl_down(ly, off);
        lw += __shfl_down(lw, off);
        lh += __shfl_down(lh, off);
        lc += __shfl_down(lc, off);
        lt += __shfl_down(lt, off);
    }
    if ((threadIdx.x & 63) == 0){
        atomicAdd(&sums[0], lx);
        atomicAdd(&sums[1], ly);
        atomicAdd(&sums[2], lw);
        atomicAdd(&sums[3], lh);
        atomicAdd(&sums[4], lc);
        atomicAdd(&sums[5], lt);
    }
}

// ---------------- Kernel 3: finalize ----------------
__global__ void finalize_k(const float* __restrict__ sums,
                           const int* __restrict__ n_obj,
                           float* __restrict__ out){
    int n = *n_obj;
    float inv = (n > 0) ? (1.0f / (float)n) : 0.0f;
    float lx = sums[0]*inv, ly = sums[1]*inv;
    float lw = sums[2]*inv, lh = sums[3]*inv;
    float lconf = sums[4]*inv;
    float ltcls = (n > 0) ? sums[5]*inv : 0.0f;
    out[0] = lx + ly + lw + lh + lconf + ltcls;
    out[1] = lx;
    out[2] = ly;
    out[3] = lw;
    out[4] = lh;
    out[5] = lconf;
    out[6] = ltcls;
}

extern "C" void kernel_launch(void* const* d_in, const int* in_sizes, int n_in,
                              void* d_out, int out_size, void* d_ws, size_t ws_size,
                              hipStream_t stream) {
    const float* input   = (const float*)d_in[0];
    const float* targets = (const float*)d_in[1];
    float* out = (float*)d_out;

    // ws layout: [0..24) 6 float sums | [24..28) int n_obj | [32..160) int counts[32]
    //            [256 ...) tdata: 32*50*12 floats (76800 B)
    float* sums   = (float*)d_ws;
    int*   n_obj  = (int*)((char*)d_ws + 24);
    int*   counts = (int*)((char*)d_ws + 32);
    float* tdata  = (float*)((char*)d_ws + 256);

    hipMemsetAsync(d_ws, 0, 256, stream);

    prep_targets<<<dim3(BS), dim3(64), 0, stream>>>(targets, tdata, counts, n_obj);

    dim3 grid(BS, (HW + 255) / 256);
    yolo_main<<<grid, dim3(256), 0, stream>>>(input, tdata, counts, sums);

    finalize_k<<<1, 1, 0, stream>>>(sums, n_obj, out);
}

// Round 2
// 127.659 us; speedup vs baseline: 2.6070x; 2.6070x over previous
//
#include <hip/hip_runtime.h>
#include <math.h>

#define BS 32
#define NT 50
#define NC 80
#define H 76
#define W 76
#define HW (H*W)
#define NA (5+NC)
#define SIGMA 8.0f
#define YBLK 23          // ceil(HW/256)
#define NBLK (BS*YBLK)   // 736

// _clog: clip(log(clip(p,1e-12,1)), -100, 0)
__device__ __forceinline__ float clog_(float p){
    p = fminf(fmaxf(p, 1e-12f), 1.0f);
    float l = logf(p);
    return fminf(fmaxf(l, -100.0f), 0.0f);
}

__device__ __forceinline__ float sigmoid_(float v){
    return 1.0f / (1.0f + expf(-v));
}

// ---------------- Kernel 1: fused prep + per-cell loss, atomic-free ----------------
// partials layout: partials[j*NBLK + bid], j in 0..5 = {x,y,w,h,conf,tcls}
// counts[b] written by the yb==0 block of each batch.
__global__ __launch_bounds__(256) void yolo_main(
    const float* __restrict__ input,
    const float* __restrict__ targets,
    float*       __restrict__ partials,
    int*         __restrict__ counts)
{
    const int b   = blockIdx.x;
    const int yb  = blockIdx.y;
    const int tid = threadIdx.x;
    const int bid = b * YBLK + yb;

    // ---- in-block target prep (redundant per block; ~50 threads, tiny) ----
    __shared__ float4 s_box[NT];         // gx1,gy1,gx2,gy2 (compacted)
    __shared__ float  s_area[NT];        // gw*gh
    __shared__ int    s_cellc[NT];       // cell id (compacted)
    __shared__ float4 s_rest[NT];        // tx,ty,tw,th
    __shared__ float2 s_sc[NT];          // scale, cls
    __shared__ int    s_cell[NT];
    __shared__ unsigned char s_valid[NT];
    __shared__ int    s_count;

    if (tid == 0) s_count = 0;

    float cls=0.f, xx=0.f, yy=0.f, ww=0.f, hh=0.f;
    bool valid = false;
    int cell0 = 0;
    if (tid < NT){
        const float* p = targets + ((size_t)b*NT + tid)*5;
        cls = p[0]; xx = p[1]; yy = p[2]; ww = p[3]; hh = p[4];
        valid = ((cls + xx + yy + ww + hh) != 0.0f);
        float gx = xx * (float)W, gy = yy * (float)H;
        int gi = min(max((int)gx, 0), W-1);
        int gj = min(max((int)gy, 0), H-1);
        cell0 = gj*W + gi;
        s_cell[tid]  = cell0;
        s_valid[tid] = valid ? 1 : 0;
    }
    __syncthreads();
    if (tid < NT && valid){
        bool dup = false;
        for (int u = 0; u < tid; ++u)
            if (s_valid[u] && s_cell[u] == cell0) dup = true;
        if (!dup){
            int idx = atomicAdd(&s_count, 1);   // LDS atomic — cheap
            float gx = xx*(float)W, gy = yy*(float)H;
            float gw = ww*(float)W, gh = hh*(float)H;
            int gi = min(max((int)gx, 0), W-1);
            int gj = min(max((int)gy, 0), H-1);
            s_box[idx]  = make_float4(gx - gw*0.5f, gy - gh*0.5f,
                                      gx + gw*0.5f, gy + gh*0.5f);
            s_area[idx] = gw * gh;
            s_cellc[idx]= cell0;
            s_rest[idx] = make_float4(gx - (float)gi, gy - (float)gj,
                                      logf(gw/SIGMA + 1e-16f),
                                      logf(gh/SIGMA + 1e-16f));
            s_sc[idx]   = make_float2(2.0f - ww*hh,
                                      (float)min(max((int)cls, 0), NC-1));
        }
    }
    __syncthreads();
    const int nb = s_count;

    // ---- per-cell loss ----
    const int cell = yb * 256 + tid;
    float lx=0.f, ly=0.f, lw=0.f, lh=0.f, lc=0.f, lt=0.f;
    if (cell < HW){
        const float* base = input + (size_t)b*NA*HW + cell;
        float vx = base[0];
        float vy = base[HW];
        float vw = base[2*HW];
        float vh = base[3*HW];
        float vc = base[4*HW];
        float x    = sigmoid_(vx);
        float y    = sigmoid_(vy);
        float conf = sigmoid_(vc);
        int i = cell / W, j = cell - i*W;
        float pw = expf(vw) * SIGMA;
        float ph = expf(vh) * SIGMA;
        float px = x + (float)j;
        float py = y + (float)i;
        float px1 = px - pw*0.5f, px2 = px + pw*0.5f;
        float py1 = py - ph*0.5f, py2 = py + ph*0.5f;
        float parea = pw * ph;

        bool ignore = false;
        int myt = -1;
        for (int t = 0; t < nb; ++t){
            float4 bx = s_box[t];               // ds_read_b128
            float garea = s_area[t];
            float iw = fminf(bx.z, px2) - fmaxf(bx.x, px1);
            float ih = fminf(bx.w, py2) - fmaxf(bx.y, py1);
            iw = fmaxf(iw, 0.f); ih = fmaxf(ih, 0.f);
            float inter = iw * ih;
            // iou >= 0.5  <=>  inter >= 0.5*(garea + parea - inter + eps), denom > 0
            ignore = ignore || (inter >= 0.5f*(garea + parea - inter + 1e-16f));
            if (s_cellc[t] == cell) myt = t;
        }

        if (myt >= 0){
            float4 r = s_rest[myt];
            float2 sc = s_sc[myt];
            float scale = sc.x;
            lx = scale * (-(r.x*clog_(x) + (1.f-r.x)*clog_(1.f-x)));
            ly = scale * (-(r.y*clog_(y) + (1.f-r.y)*clog_(1.f-y)));
            float dw = fabsf(vw - r.z);
            lw = scale * (dw < 1.f ? 0.5f*dw*dw : dw - 0.5f);
            float dh = fabsf(vh - r.w);
            lh = scale * (dh < 1.f ? 0.5f*dh*dh : dh - 0.5f);
            lc = -clog_(conf);
            int cidx = (int)sc.y;
            const float* cb = base + 5*HW;
            float acc = 0.f;
            for (int c = 0; c < NC; ++c){
                float pc = sigmoid_(cb[(size_t)c*HW]);
                if (c == cidx) acc += -clog_(pc);
                else           acc += -clog_(1.f - pc);
            }
            lt = acc;
        } else if (!ignore){
            lc = 0.5f * (-clog_(1.0f - conf));
        }
    }

    // ---- block reduction: wave shuffle, then cross-wave via LDS, plain stores ----
    #pragma unroll
    for (int off = 32; off > 0; off >>= 1){
        lx += __shfl_down(lx, off);
        ly += __shfl_down(ly, off);
        lw += __shfl_down(lw, off);
        lh += __shfl_down(lh, off);
        lc += __shfl_down(lc, off);
        lt += __shfl_down(lt, off);
    }
    __shared__ float s_red[4*6];
    if ((tid & 63) == 0){
        int wv = tid >> 6;
        s_red[wv*6+0] = lx; s_red[wv*6+1] = ly; s_red[wv*6+2] = lw;
        s_red[wv*6+3] = lh; s_red[wv*6+4] = lc; s_red[wv*6+5] = lt;
    }
    __syncthreads();
    if (tid < 6){
        float v = s_red[tid] + s_red[6+tid] + s_red[12+tid] + s_red[18+tid];
        partials[tid*NBLK + bid] = v;          // block-unique slot, no atomics
    }
    if (yb == 0 && tid == 0) counts[b] = nb;
}

// ---------------- Kernel 2: final reduce over 736 blocks + n_obj + output ----------------
__global__ __launch_bounds__(256) void finalize_k(
    const float* __restrict__ partials,
    const int*   __restrict__ counts,
    float*       __restrict__ out)
{
    int tid = threadIdx.x;
    float loc[6] = {0,0,0,0,0,0};
    for (int k = tid; k < NBLK; k += 256){
        #pragma unroll
        for (int j = 0; j < 6; ++j) loc[j] += partials[j*NBLK + k];
    }
    float nloc = (tid < BS) ? (float)counts[tid] : 0.f;

    #pragma unroll
    for (int off = 32; off > 0; off >>= 1){
        #pragma unroll
        for (int j = 0; j < 6; ++j) loc[j] += __shfl_down(loc[j], off);
        nloc += __shfl_down(nloc, off);
    }
    __shared__ float s_red[4*7];
    if ((tid & 63) == 0){
        int wv = tid >> 6;
        #pragma unroll
        for (int j = 0; j < 6; ++j) s_red[wv*7+j] = loc[j];
        s_red[wv*7+6] = nloc;
    }
    __syncthreads();
    if (tid == 0){
        float s[7];
        #pragma unroll
        for (int j = 0; j < 7; ++j)
            s[j] = s_red[j] + s_red[7+j] + s_red[14+j] + s_red[21+j];
        float n = s[6];
        float inv = (n > 0.f) ? (1.0f / n) : 0.0f;
        float lx = s[0]*inv, ly = s[1]*inv, lw = s[2]*inv, lh = s[3]*inv;
        float lconf = s[4]*inv;
        float ltcls = (n > 0.f) ? s[5]*inv : 0.0f;
        out[0] = lx + ly + lw + lh + lconf + ltcls;
        out[1] = lx;
        out[2] = ly;
        out[3] = lw;
        out[4] = lh;
        out[5] = lconf;
        out[6] = ltcls;
    }
}

extern "C" void kernel_launch(void* const* d_in, const int* in_sizes, int n_in,
                              void* d_out, int out_size, void* d_ws, size_t ws_size,
                              hipStream_t stream) {
    const float* input   = (const float*)d_in[0];
    const float* targets = (const float*)d_in[1];
    float* out = (float*)d_out;

    // ws layout: [0 .. 6*NBLK*4) partials | then counts[32]
    float* partials = (float*)d_ws;
    int*   counts   = (int*)((char*)d_ws + 6*NBLK*sizeof(float));

    dim3 grid(BS, YBLK);
    yolo_main<<<grid, dim3(256), 0, stream>>>(input, targets, partials, counts);
    finalize_k<<<1, dim3(256), 0, stream>>>(partials, counts, out);
}